// Round 7
// baseline (153.666 us; speedup 1.0000x reference)
//
#include <hip/hip_runtime.h>

#define NHEAD 12
#define DHEAD 64
#define SEQ   2048
#define NB    2
#define NX    768
#define MTOK  (NB * SEQ)   // 4096

typedef __attribute__((ext_vector_type(8))) short short8;
typedef __attribute__((ext_vector_type(4))) short short4v;
typedef __attribute__((ext_vector_type(4))) float f32x4;

__device__ __forceinline__ unsigned short f2bf(float x) {
    union { float f; unsigned u; } v; v.f = x;
    unsigned r = v.u + 0x7fffu + ((v.u >> 16) & 1u);
    return (unsigned short)(r >> 16);
}

// v_cvt_pk_bf16_f32: low16 = bf16(a), high16 = bf16(b); RNE on gfx950
__device__ __forceinline__ unsigned pkbf(float a, float b) {
    unsigned r;
    asm("v_cvt_pk_bf16_f32 %0, %1, %2" : "=v"(r) : "v"(a), "v"(b));
    return r;
}

// raw 2^x (single v_exp_f32; scores are bounded so no range fixup needed)
__device__ __forceinline__ float fexp2(float x) {
#if __has_builtin(__builtin_amdgcn_exp2f)
    return __builtin_amdgcn_exp2f(x);
#else
    float r; asm("v_exp_f32 %0, %1" : "=v"(r) : "v"(x)); return r;
#endif
}

#define MFMA32(a, b, c) __builtin_amdgcn_mfma_f32_16x16x32_bf16(a, b, c, 0, 0, 0)

// ---------------------------------------------------------------------------
// Merged converts (one dispatch; block-uniform branch):
//   blocks [0,3072):     hs fp32 -> Abf bf16 elementwise (float4/ushort4)
//   blocks [3072,4800):  w_attn [768,2304] -> WtA [2304,768] bf16 transpose
//   blocks [4800,5376):  w_proj [768,768]  -> WtP [768,768]  bf16 transpose
// ---------------------------------------------------------------------------
__global__ __launch_bounds__(256)
void cvt_all(const float* __restrict__ hs,
             const float* __restrict__ wa, const float* __restrict__ wp,
             unsigned short* __restrict__ Abf,
             unsigned short* __restrict__ WtA, unsigned short* __restrict__ WtP)
{
    __shared__ float tile[32][33];
    const int bid = blockIdx.x;
    const int t = threadIdx.x;

    if (bid < 3072) {
        int i = bid * 256 + t;
        if (i >= 786432) return;
        float4 v = ((const float4*)hs)[i];
        ushort4 o;
        o.x = f2bf(v.x); o.y = f2bf(v.y); o.z = f2bf(v.z); o.w = f2bf(v.w);
        ((ushort4*)Abf)[i] = o;
        return;
    }

    const float* W; unsigned short* T; int K, N, bx, by;
    if (bid < 4800) {
        int b2 = bid - 3072;               // 72 x 24
        bx = b2 % 72; by = b2 / 72;
        W = wa; T = WtA; K = NX; N = 3 * NX;
    } else {
        int b2 = bid - 4800;               // 24 x 24
        bx = b2 % 24; by = b2 / 24;
        W = wp; T = WtP; K = NX; N = NX;
    }
    const int r = t >> 5, c = t & 31;
    const int k0 = by * 32, n0 = bx * 32;
#pragma unroll
    for (int i = 0; i < 4; i++)
        tile[r + i * 8][c] = W[(size_t)(k0 + r + i * 8) * N + n0 + c];
    __syncthreads();
#pragma unroll
    for (int i = 0; i < 4; i++) {
        int n = r + i * 8;
        T[(size_t)(n0 + n) * K + k0 + c] = f2bf(tile[c][n]);
    }
}

// ---------------------------------------------------------------------------
// bf16 MFMA GEMM: C[M,N] = A[M,K] @ Bt[N,K]^T + bias.
// XCD-chunked block swizzle (T1; grids 576/192 are %8==0).
// MODE 0: QKV epilogue. q,k scalar-store path unchanged; V path NEW:
//         LDS-transposed coalesced stores (sm is free after the K loop).
// MODE 1: fp32 out + bias.
// ---------------------------------------------------------------------------
template<int MODE>
__global__ __launch_bounds__(256, 3)
void gemm_bf(const unsigned short* __restrict__ A,   // [M][K] bf16
             const unsigned short* __restrict__ Bt,  // [N][K] bf16
             const float* __restrict__ bias,
             float* __restrict__ fo,
             unsigned short* __restrict__ qb, unsigned short* __restrict__ kb2,
             unsigned short* __restrict__ vtb,
             int M, int N, int K)
{
    __shared__ __align__(16) unsigned char sm[2][16384];  // [buf][A 8KB | B 8KB]
    const int t = threadIdx.x;
    const int w = t >> 6, lane = t & 63;
    const int lo16 = lane & 15, quad = lane >> 4;

    // XCD-chunked swizzle (nwg % 8 == 0 for both call sites)
    const int nwg  = gridDim.x * gridDim.y;
    const int flat = blockIdx.y * gridDim.x + blockIdx.x;
    const int swz  = (flat & 7) * (nwg >> 3) + (flat >> 3);
    const int ib = (swz / gridDim.x) * 128, jb = (swz % gridDim.x) * 128;

    f32x4 acc[4][4];
#pragma unroll
    for (int mt = 0; mt < 4; mt++)
#pragma unroll
        for (int nt = 0; nt < 4; nt++) acc[mt][nt] = (f32x4){0.f, 0.f, 0.f, 0.f};

    const int srow = lane >> 2;   // 0..15 within seg
    const int sj   = lane & 3;

    auto stage = [&](int buf, int k0) {
#pragma unroll
        for (int i = 0; i < 4; i++) {
            const int u   = i * 4 + w;
            const int p   = u >> 3;
            const int row = (u & 7) * 16 + srow;
            const int sc  = sj ^ (row & 3);
            const unsigned short* g = (p == 0)
                ? (A  + (size_t)(ib + row) * K + k0 + sc * 8)
                : (Bt + (size_t)(jb + row) * K + k0 + sc * 8);
            void* lp = &sm[buf][p * 8192 + (u & 7) * 1024];
            __builtin_amdgcn_global_load_lds(
                (const __attribute__((address_space(1))) unsigned int*)g,
                (__attribute__((address_space(3))) unsigned int*)lp, 16, 0, 0);
        }
    };

    const int mrow = (w >> 1) * 64;
    const int nrow = (w & 1) * 64;

    stage(0, 0);
    const int NIT = K / 32;
    for (int kt = 0; kt < NIT; kt++) {
        const int buf = kt & 1;
        __syncthreads();
        if (kt + 1 < NIT) stage(buf ^ 1, (kt + 1) * 32);

        short8 af[4], bf[4];
#pragma unroll
        for (int mt = 0; mt < 4; mt++) {
            const int row = mrow + mt * 16 + lo16;
            af[mt] = *(const short8*)&sm[buf][row * 64 + ((quad ^ (row & 3)) * 16)];
        }
#pragma unroll
        for (int nt = 0; nt < 4; nt++) {
            const int row = nrow + nt * 16 + lo16;
            bf[nt] = *(const short8*)&sm[buf][8192 + row * 64 + ((quad ^ (row & 3)) * 16)];
        }
#pragma unroll
        for (int mt = 0; mt < 4; mt++)
#pragma unroll
            for (int nt = 0; nt < 4; nt++)
                acc[mt][nt] = MFMA32(af[mt], bf[nt], acc[mt][nt]);
    }

    if constexpr (MODE == 0) {
        const int which = jb / NX;   // 0=q 1=k 2=v, uniform per block
        if (which == 2) {
            // ---- V epilogue: LDS transpose -> coalesced stores ----
            // Logical smT[j'][m'] bf16 (128x128 = 32KB), 16B-chunk XOR swizzle:
            // chunk (m'>>3) of row j' lives at chunk ((m'>>3) ^ (j'&15)).
            __syncthreads();             // all waves done reading sm
            char* smT = (char*)sm;
#pragma unroll
            for (int nt = 0; nt < 4; nt++) {
                const int jl = nrow + nt * 16 + lo16;          // j' 0..127
                const float bj = bias[jb + jl];
#pragma unroll
                for (int mt = 0; mt < 4; mt++) {
                    const int dw0 = (mrow >> 1) + mt * 8 + quad * 2;  // m'/2
                    const int dws = dw0 ^ ((jl & 15) << 2);
                    ushort4 pv;
                    pv.x = f2bf(acc[mt][nt][0] + bj);
                    pv.y = f2bf(acc[mt][nt][1] + bj);
                    pv.z = f2bf(acc[mt][nt][2] + bj);
                    pv.w = f2bf(acc[mt][nt][3] + bj);
                    *(ushort4*)(smT + jl * 256 + dws * 4) = pv;
                }
            }
            __syncthreads();
            const int bb2 = ib >> 11, sbase = ib & 2047;
#pragma unroll
            for (int i = 0; i < 8; i++) {
                const int idx = i * 256 + t;       // 0..2047
                const int jr  = idx >> 4;          // j' 0..127
                const int c8  = idx & 15;          // m' 16B chunk
                const int pc  = c8 ^ (jr & 15);
                short8 vv = *(const short8*)(smT + jr * 256 + pc * 16);
                const int cc2 = jb - 2 * NX + jr;
                const int hh2 = cc2 >> 6, dd2 = cc2 & 63;
                *(short8*)(vtb + ((size_t)(bb2 * NHEAD + hh2) * DHEAD + dd2) * SEQ
                           + sbase + c8 * 8) = vv;
            }
        } else {
#pragma unroll
            for (int nt = 0; nt < 4; nt++) {
                const int j  = jb + nrow + nt * 16 + lo16;
                const int cc = j - which * NX;
                const int hh = cc >> 6, dd = cc & 63;
                const float bj = bias[j];
#pragma unroll
                for (int mt = 0; mt < 4; mt++) {
                    const int m0 = ib + mrow + mt * 16 + quad * 4;
                    const int bb = m0 >> 11;
                    const int s0 = m0 & 2047;
                    const size_t hb = (size_t)(bb * NHEAD + hh);
                    unsigned short* dst = (which == 0) ? qb : kb2;
                    // q: fold softmax scale AND log2(e) -> attn does 2^s
                    const float sc = (which == 0) ? 0.18033688011112042f : 1.0f;
#pragma unroll
                    for (int r = 0; r < 4; r++)
                        dst[(hb * SEQ + s0 + r) * DHEAD + dd] =
                            f2bf((acc[mt][nt][r] + bj) * sc);
                }
            }
        }
    } else {
#pragma unroll
        for (int nt = 0; nt < 4; nt++) {
            const int j  = jb + nrow + nt * 16 + lo16;
            const float bj = bias[j];
#pragma unroll
            for (int mt = 0; mt < 4; mt++) {
                const int m0 = ib + mrow + mt * 16 + quad * 4;
#pragma unroll
                for (int r = 0; r < 4; r++)
                    fo[(size_t)(m0 + r) * N + j] = acc[mt][nt][r] + bj;
            }
        }
    }
}

// ---------------------------------------------------------------------------
// bf16 flash attention — R6-verified kernel (45.0 us, absmax 2.44e-4,
// 0 bank conflicts). ONLY delta vs R6: P-pack via v_cvt_pk_bf16_f32
// (8 instrs) instead of manual f2bf bit-twiddle (~72 VALU ops/iter).
// Key-relabeled staging (sigma bit-permutation) so both QK and PV are
// 2x ds_read_b128 + 2x MFMA32 with identical conflict-free patterns.
// ---------------------------------------------------------------------------
__global__ __launch_bounds__(256, 3)
void attn_bf(const unsigned short* __restrict__ qb, const unsigned short* __restrict__ kb,
             const unsigned short* __restrict__ vtb, unsigned short* __restrict__ ab)
{
    __shared__ __align__(16) unsigned char sm[2][16384];  // [buf][K 8KB | V 8KB]
    const int t = threadIdx.x;
    const int w = t >> 6, lane = t & 63;
    const int lo16 = lane & 15, quad = lane >> 4;

    // XCD-swizzled decode: same bh stays on one XCD for K/V L2 locality
    const int id = blockIdx.x;            // 768
    const int xcd = id & 7, slot = id >> 3;
    const int bh = xcd * 3 + slot % 3;
    const int q0 = (slot / 3) * 64;
    const int b = bh / NHEAD, h = bh % NHEAD;

    const unsigned short* Qb = qb  + (size_t)bh * SEQ * DHEAD;
    const unsigned short* Kb = kb  + (size_t)bh * SEQ * DHEAD;
    const unsigned short* Vb = vtb + (size_t)bh * DHEAD * SEQ;

    // Q^T B-fragment: query = q0 + w*16 + lo16, dims quad*8..+8 per half
    short8 qf[2];
    {
        const size_t qo = (size_t)(q0 + w * 16 + lo16) * DHEAD + quad * 8;
        qf[0] = *(const short8*)(Qb + qo);
        qf[1] = *(const short8*)(Qb + qo + 32);
    }

    // staging: 16 segs of 1KB (K: u=0..7, V: u=8..15); row pitch 128 B
    // (8 chunks of 16 B); LDS chunk j of LDS-row l holds global chunk
    // j^(l&7). K rows are globally relabeled by sigma (bijective).
    const int srow = lane >> 3;   // 0..7 within seg
    const int sj   = lane & 7;
    auto stage = [&](int buf, int k0) {
#pragma unroll
        for (int i = 0; i < 4; i++) {
            const int u   = i * 4 + w;
            const int p   = u >> 3;
            const int row = (u & 7) * 8 + srow;   // LDS row (K key slot / V dim)
            const int sc  = sj ^ (row & 7);
            // K: global key = sigma(row); V: dim row unpermuted
            const int gr  = (row & 32) | (((row >> 2) & 3) << 3)
                          | (((row >> 4) & 1) << 2) | (row & 3);
            const unsigned short* g = (p == 0)
                ? (Kb + (size_t)(k0 + gr) * DHEAD + sc * 8)
                : (Vb + (size_t)row * SEQ + k0 + sc * 8);
            void* lp = &sm[buf][p * 8192 + (u & 7) * 1024];
            __builtin_amdgcn_global_load_lds(
                (const __attribute__((address_space(1))) unsigned int*)g,
                (__attribute__((address_space(3))) unsigned int*)lp, 16, 0, 0);
        }
    };

    f32x4 oacc[4];
#pragma unroll
    for (int dt = 0; dt < 4; dt++) oacc[dt] = (f32x4){0.f, 0.f, 0.f, 0.f};
    float lsum = 0.f;

    stage(0, 0);
    for (int kt = 0; kt < SEQ / 64; kt++) {
        const int buf = kt & 1;
        __syncthreads();
        if (kt + 1 < SEQ / 64) stage(buf ^ 1, (kt + 1) * 64);

        // ---- S^T = K @ Q^T: 4 key-subtiles of 16 (LDS-row order) ----
        f32x4 s[4];
#pragma unroll
        for (int rt = 0; rt < 4; rt++) {
            const int row = rt * 16 + lo16;
            const int rs = row & 7;
            short8 kf0 = *(const short8*)&sm[buf][row * 128 + ((quad ^ rs) * 16)];
            short8 kf1 = *(const short8*)&sm[buf][row * 128 + (((4 + quad) ^ rs) * 16)];
            f32x4 a = (f32x4){0.f, 0.f, 0.f, 0.f};
            a = MFMA32(kf0, qf[0], a);
            a = MFMA32(kf1, qf[1], a);
            s[rt] = a;
        }

        // ---- 2^s + cvt_pk pack into two MFMA32 B-frags ----
        // pf[f] dwords: {pk(e[2f][0],e[2f][1]), pk(e[2f][2],e[2f][3]),
        //                pk(e[2f+1][0],e[2f+1][1]), pk(e[2f+1][2],e[2f+1][3])}
        short8 pf[2];
#pragma unroll
        for (int f = 0; f < 2; f++) {
            float e0 = fexp2(s[2 * f][0]),     e1 = fexp2(s[2 * f][1]);
            float e2 = fexp2(s[2 * f][2]),     e3 = fexp2(s[2 * f][3]);
            float e4 = fexp2(s[2 * f + 1][0]), e5 = fexp2(s[2 * f + 1][1]);
            float e6 = fexp2(s[2 * f + 1][2]), e7 = fexp2(s[2 * f + 1][3]);
            lsum += ((e0 + e1) + (e2 + e3)) + ((e4 + e5) + (e6 + e7));
            union { short8 s8; unsigned u[4]; } pk;
            pk.u[0] = pkbf(e0, e1);
            pk.u[1] = pkbf(e2, e3);
            pk.u[2] = pkbf(e4, e5);
            pk.u[3] = pkbf(e6, e7);
            pf[f] = pk.s8;
        }

        // ---- O^T += V^T @ P^T: 2 MFMA32 per dim-subtile ----
        __builtin_amdgcn_s_setprio(1);
#pragma unroll
        for (int dt = 0; dt < 4; dt++) {
            const int row = dt * 16 + lo16;
            const int rs = row & 7;
            short8 vf0 = *(const short8*)&sm[buf][8192 + row * 128 + ((quad ^ rs) * 16)];
            short8 vf1 = *(const short8*)&sm[buf][8192 + row * 128 + (((4 + quad) ^ rs) * 16)];
            f32x4 a = oacc[dt];
            a = MFMA32(vf0, pf[0], a);
            a = MFMA32(vf1, pf[1], a);
            oacc[dt] = a;
        }
        __builtin_amdgcn_s_setprio(0);
    }

    // deferred l reduction across quads (each quad covered disjoint keys)
    lsum += __shfl_xor(lsum, 16);
    lsum += __shfl_xor(lsum, 32);
    const float inv = 1.0f / lsum;

    // O^T[dim = dt*16 + quad*4 + r][query = lo16] -> ab bf16 [B,S,NX]
    unsigned short* dst = ab + (size_t)(b * SEQ + q0 + w * 16 + lo16) * NX + h * DHEAD;
#pragma unroll
    for (int dt = 0; dt < 4; dt++) {
        ushort4 pv;
        pv.x = f2bf(oacc[dt][0] * inv);
        pv.y = f2bf(oacc[dt][1] * inv);
        pv.z = f2bf(oacc[dt][2] * inv);
        pv.w = f2bf(oacc[dt][3] * inv);
        *(ushort4*)(dst + dt * 16 + quad * 4) = pv;
    }
}

// ---------------------------------------------------------------------------
extern "C" void kernel_launch(void* const* d_in, const int* in_sizes, int n_in,
                              void* d_out, int out_size, void* d_ws, size_t ws_size,
                              hipStream_t stream)
{
    const float* hs     = (const float*)d_in[0];
    const float* w_attn = (const float*)d_in[1];
    const float* b_attn = (const float*)d_in[2];
    const float* w_proj = (const float*)d_in[3];
    const float* b_proj = (const float*)d_in[4];
    float* out = (float*)d_out;

    unsigned short* wsu = (unsigned short*)d_ws;
    unsigned short* Abf  = wsu;                      // 4096*768
    unsigned short* WtA  = Abf  + 3145728;           // 2304*768
    unsigned short* WtP  = WtA  + 1769472;           // 768*768
    unsigned short* qbuf = WtP  + 589824;            // [B,H,S,D]
    unsigned short* kbuf = qbuf + 3145728;           // [B,H,S,D]
    unsigned short* vtbf = kbuf + 3145728;           // [B,H,D,S]
    unsigned short* abf  = vtbf + 3145728;           // [B,S,NX] bf16

    // merged converts (one dispatch)
    cvt_all<<<5376, 256, 0, stream>>>(hs, w_attn, w_proj, Abf, WtA, WtP);

    // QKV GEMM
    gemm_bf<0><<<dim3(18, 32), 256, 0, stream>>>(
        Abf, WtA, b_attn, nullptr, qbuf, kbuf, vtbf, MTOK, 3 * NX, NX);

    // attention
    attn_bf<<<768, 256, 0, stream>>>(qbuf, kbuf, vtbf, abf);

    // output projection
    gemm_bf<1><<<dim3(6, 32), 256, 0, stream>>>(
        abf, WtP, b_proj, out, nullptr, nullptr, nullptr, MTOK, NX, NX);
}

// Round 8
// 150.227 us; speedup vs baseline: 1.0229x; 1.0229x over previous
//
#include <hip/hip_runtime.h>

#define NHEAD 12
#define DHEAD 64
#define SEQ   2048
#define NB    2
#define NX    768
#define MTOK  (NB * SEQ)   // 4096

typedef __attribute__((ext_vector_type(8))) short short8;
typedef __attribute__((ext_vector_type(4))) short short4v;
typedef __attribute__((ext_vector_type(4))) float f32x4;

__device__ __forceinline__ unsigned short f2bf(float x) {
    union { float f; unsigned u; } v; v.f = x;
    unsigned r = v.u + 0x7fffu + ((v.u >> 16) & 1u);
    return (unsigned short)(r >> 16);
}

// v_cvt_pk_bf16_f32: low16 = bf16(a), high16 = bf16(b); RNE on gfx950
__device__ __forceinline__ unsigned pkbf(float a, float b) {
    unsigned r;
    asm("v_cvt_pk_bf16_f32 %0, %1, %2" : "=v"(r) : "v"(a), "v"(b));
    return r;
}

// raw 2^x (single v_exp_f32; scores are bounded so no range fixup needed)
__device__ __forceinline__ float fexp2(float x) {
#if __has_builtin(__builtin_amdgcn_exp2f)
    return __builtin_amdgcn_exp2f(x);
#else
    float r; asm("v_exp_f32 %0, %1" : "=v"(r) : "v"(x)); return r;
#endif
}

#define MFMA32(a, b, c) __builtin_amdgcn_mfma_f32_16x16x32_bf16(a, b, c, 0, 0, 0)

// ---------------------------------------------------------------------------
// Merged converts (one dispatch; block-uniform branch):
//   blocks [0,3072):     hs fp32 -> Abf bf16 elementwise (float4/ushort4)
//   blocks [3072,4800):  w_attn [768,2304] -> WtA [2304,768] bf16 transpose
//   blocks [4800,5376):  w_proj [768,768]  -> WtP [768,768]  bf16 transpose
// ---------------------------------------------------------------------------
__global__ __launch_bounds__(256)
void cvt_all(const float* __restrict__ hs,
             const float* __restrict__ wa, const float* __restrict__ wp,
             unsigned short* __restrict__ Abf,
             unsigned short* __restrict__ WtA, unsigned short* __restrict__ WtP)
{
    __shared__ float tile[32][33];
    const int bid = blockIdx.x;
    const int t = threadIdx.x;

    if (bid < 3072) {
        int i = bid * 256 + t;
        if (i >= 786432) return;
        float4 v = ((const float4*)hs)[i];
        ushort4 o;
        o.x = f2bf(v.x); o.y = f2bf(v.y); o.z = f2bf(v.z); o.w = f2bf(v.w);
        ((ushort4*)Abf)[i] = o;
        return;
    }

    const float* W; unsigned short* T; int K, N, bx, by;
    if (bid < 4800) {
        int b2 = bid - 3072;               // 72 x 24
        bx = b2 % 72; by = b2 / 72;
        W = wa; T = WtA; K = NX; N = 3 * NX;
    } else {
        int b2 = bid - 4800;               // 24 x 24
        bx = b2 % 24; by = b2 / 24;
        W = wp; T = WtP; K = NX; N = NX;
    }
    const int r = t >> 5, c = t & 31;
    const int k0 = by * 32, n0 = bx * 32;
#pragma unroll
    for (int i = 0; i < 4; i++)
        tile[r + i * 8][c] = W[(size_t)(k0 + r + i * 8) * N + n0 + c];
    __syncthreads();
#pragma unroll
    for (int i = 0; i < 4; i++) {
        int n = r + i * 8;
        T[(size_t)(n0 + n) * K + k0 + c] = f2bf(tile[c][n]);
    }
}

// ---------------------------------------------------------------------------
// bf16 MFMA GEMM: C[M,N] = A[M,K] @ Bt[N,K]^T + bias.
// XCD-chunked block swizzle (T1; grids 576/192 are %8==0).
// MODE 0: QKV epilogue (q,k [B,H,S,D] bf16; q scaled by 0.125*log2(e) so the
//         attention kernel computes softmax via raw 2^s; v -> [B,H,D,S] bf16).
//         Scalar-store form (R6-verified) — R7's LDS-transpose V path cost
//         ~3-4 us: scattered stores were latency-hidden, barriers were not.
// MODE 1: fp32 out + bias.
// ---------------------------------------------------------------------------
template<int MODE>
__global__ __launch_bounds__(256, 3)
void gemm_bf(const unsigned short* __restrict__ A,   // [M][K] bf16
             const unsigned short* __restrict__ Bt,  // [N][K] bf16
             const float* __restrict__ bias,
             float* __restrict__ fo,
             unsigned short* __restrict__ qb, unsigned short* __restrict__ kb2,
             unsigned short* __restrict__ vtb,
             int M, int N, int K)
{
    __shared__ __align__(16) unsigned char sm[2][16384];  // [buf][A 8KB | B 8KB]
    const int t = threadIdx.x;
    const int w = t >> 6, lane = t & 63;
    const int lo16 = lane & 15, quad = lane >> 4;

    // XCD-chunked swizzle (nwg % 8 == 0 for both call sites)
    const int nwg  = gridDim.x * gridDim.y;
    const int flat = blockIdx.y * gridDim.x + blockIdx.x;
    const int swz  = (flat & 7) * (nwg >> 3) + (flat >> 3);
    const int ib = (swz / gridDim.x) * 128, jb = (swz % gridDim.x) * 128;

    f32x4 acc[4][4];
#pragma unroll
    for (int mt = 0; mt < 4; mt++)
#pragma unroll
        for (int nt = 0; nt < 4; nt++) acc[mt][nt] = (f32x4){0.f, 0.f, 0.f, 0.f};

    const int srow = lane >> 2;   // 0..15 within seg
    const int sj   = lane & 3;

    auto stage = [&](int buf, int k0) {
#pragma unroll
        for (int i = 0; i < 4; i++) {
            const int u   = i * 4 + w;
            const int p   = u >> 3;
            const int row = (u & 7) * 16 + srow;
            const int sc  = sj ^ (row & 3);
            const unsigned short* g = (p == 0)
                ? (A  + (size_t)(ib + row) * K + k0 + sc * 8)
                : (Bt + (size_t)(jb + row) * K + k0 + sc * 8);
            void* lp = &sm[buf][p * 8192 + (u & 7) * 1024];
            __builtin_amdgcn_global_load_lds(
                (const __attribute__((address_space(1))) unsigned int*)g,
                (__attribute__((address_space(3))) unsigned int*)lp, 16, 0, 0);
        }
    };

    const int mrow = (w >> 1) * 64;
    const int nrow = (w & 1) * 64;

    stage(0, 0);
    const int NIT = K / 32;
    for (int kt = 0; kt < NIT; kt++) {
        const int buf = kt & 1;
        __syncthreads();
        if (kt + 1 < NIT) stage(buf ^ 1, (kt + 1) * 32);

        short8 af[4], bf[4];
#pragma unroll
        for (int mt = 0; mt < 4; mt++) {
            const int row = mrow + mt * 16 + lo16;
            af[mt] = *(const short8*)&sm[buf][row * 64 + ((quad ^ (row & 3)) * 16)];
        }
#pragma unroll
        for (int nt = 0; nt < 4; nt++) {
            const int row = nrow + nt * 16 + lo16;
            bf[nt] = *(const short8*)&sm[buf][8192 + row * 64 + ((quad ^ (row & 3)) * 16)];
        }
#pragma unroll
        for (int mt = 0; mt < 4; mt++)
#pragma unroll
            for (int nt = 0; nt < 4; nt++)
                acc[mt][nt] = MFMA32(af[mt], bf[nt], acc[mt][nt]);
    }

    if constexpr (MODE == 0) {
        const int which = jb / NX;   // 0=q 1=k 2=v, uniform per block
#pragma unroll
        for (int nt = 0; nt < 4; nt++) {
            const int j  = jb + nrow + nt * 16 + lo16;
            const int cc = j - which * NX;
            const int hh = cc >> 6, dd = cc & 63;
            const float bj = bias[j];
#pragma unroll
            for (int mt = 0; mt < 4; mt++) {
                const int m0 = ib + mrow + mt * 16 + quad * 4;
                const int bb = m0 >> 11;
                const int s0 = m0 & 2047;
                const size_t hb = (size_t)(bb * NHEAD + hh);
                if (which == 2) {
                    ushort4 pv;
                    pv.x = f2bf(acc[mt][nt][0] + bj);
                    pv.y = f2bf(acc[mt][nt][1] + bj);
                    pv.z = f2bf(acc[mt][nt][2] + bj);
                    pv.w = f2bf(acc[mt][nt][3] + bj);
                    *(ushort4*)(vtb + (hb * DHEAD + dd) * SEQ + s0) = pv;
                } else {
                    unsigned short* dst = (which == 0) ? qb : kb2;
                    // q: fold softmax scale AND log2(e) -> attn does 2^s
                    const float sc = (which == 0) ? 0.18033688011112042f : 1.0f;
#pragma unroll
                    for (int r = 0; r < 4; r++)
                        dst[(hb * SEQ + s0 + r) * DHEAD + dd] =
                            f2bf((acc[mt][nt][r] + bj) * sc);
                }
            }
        }
    } else {
#pragma unroll
        for (int nt = 0; nt < 4; nt++) {
            const int j  = jb + nrow + nt * 16 + lo16;
            const float bj = bias[j];
#pragma unroll
            for (int mt = 0; mt < 4; mt++) {
                const int m0 = ib + mrow + mt * 16 + quad * 4;
#pragma unroll
                for (int r = 0; r < 4; r++)
                    fo[(size_t)(m0 + r) * N + j] = acc[mt][nt][r] + bj;
            }
        }
    }
}

// ---------------------------------------------------------------------------
// bf16 flash attention — R6-verified structure + R7-verified cvt_pk P-pack
// (45.0 -> ~43.5 us, absmax 2.44e-4, 0 bank conflicts).
// Key-relabeled staging (sigma bit-permutation) so both QK and PV are
// 2x ds_read_b128 + 2x MFMA32 with identical conflict-free patterns.
// exp2-fold (scale*log2e in q), setprio around PV, XCD-swizzled decode.
// ---------------------------------------------------------------------------
__global__ __launch_bounds__(256, 3)
void attn_bf(const unsigned short* __restrict__ qb, const unsigned short* __restrict__ kb,
             const unsigned short* __restrict__ vtb, unsigned short* __restrict__ ab)
{
    __shared__ __align__(16) unsigned char sm[2][16384];  // [buf][K 8KB | V 8KB]
    const int t = threadIdx.x;
    const int w = t >> 6, lane = t & 63;
    const int lo16 = lane & 15, quad = lane >> 4;

    // XCD-swizzled decode: same bh stays on one XCD for K/V L2 locality
    const int id = blockIdx.x;            // 768
    const int xcd = id & 7, slot = id >> 3;
    const int bh = xcd * 3 + slot % 3;
    const int q0 = (slot / 3) * 64;
    const int b = bh / NHEAD, h = bh % NHEAD;

    const unsigned short* Qb = qb  + (size_t)bh * SEQ * DHEAD;
    const unsigned short* Kb = kb  + (size_t)bh * SEQ * DHEAD;
    const unsigned short* Vb = vtb + (size_t)bh * DHEAD * SEQ;

    // Q^T B-fragment: query = q0 + w*16 + lo16, dims quad*8..+8 per half
    short8 qf[2];
    {
        const size_t qo = (size_t)(q0 + w * 16 + lo16) * DHEAD + quad * 8;
        qf[0] = *(const short8*)(Qb + qo);
        qf[1] = *(const short8*)(Qb + qo + 32);
    }

    // staging: 16 segs of 1KB (K: u=0..7, V: u=8..15); row pitch 128 B
    // (8 chunks of 16 B); LDS chunk j of LDS-row l holds global chunk
    // j^(l&7). K rows are globally relabeled by sigma (bijective).
    const int srow = lane >> 3;   // 0..7 within seg
    const int sj   = lane & 7;
    auto stage = [&](int buf, int k0) {
#pragma unroll
        for (int i = 0; i < 4; i++) {
            const int u   = i * 4 + w;
            const int p   = u >> 3;
            const int row = (u & 7) * 8 + srow;   // LDS row (K key slot / V dim)
            const int sc  = sj ^ (row & 7);
            // K: global key = sigma(row); V: dim row unpermuted
            const int gr  = (row & 32) | (((row >> 2) & 3) << 3)
                          | (((row >> 4) & 1) << 2) | (row & 3);
            const unsigned short* g = (p == 0)
                ? (Kb + (size_t)(k0 + gr) * DHEAD + sc * 8)
                : (Vb + (size_t)row * SEQ + k0 + sc * 8);
            void* lp = &sm[buf][p * 8192 + (u & 7) * 1024];
            __builtin_amdgcn_global_load_lds(
                (const __attribute__((address_space(1))) unsigned int*)g,
                (__attribute__((address_space(3))) unsigned int*)lp, 16, 0, 0);
        }
    };

    f32x4 oacc[4];
#pragma unroll
    for (int dt = 0; dt < 4; dt++) oacc[dt] = (f32x4){0.f, 0.f, 0.f, 0.f};
    float lsum = 0.f;

    stage(0, 0);
    for (int kt = 0; kt < SEQ / 64; kt++) {
        const int buf = kt & 1;
        __syncthreads();
        if (kt + 1 < SEQ / 64) stage(buf ^ 1, (kt + 1) * 64);

        // ---- S^T = K @ Q^T: 4 key-subtiles of 16 (LDS-row order) ----
        f32x4 s[4];
#pragma unroll
        for (int rt = 0; rt < 4; rt++) {
            const int row = rt * 16 + lo16;
            const int rs = row & 7;
            short8 kf0 = *(const short8*)&sm[buf][row * 128 + ((quad ^ rs) * 16)];
            short8 kf1 = *(const short8*)&sm[buf][row * 128 + (((4 + quad) ^ rs) * 16)];
            f32x4 a = (f32x4){0.f, 0.f, 0.f, 0.f};
            a = MFMA32(kf0, qf[0], a);
            a = MFMA32(kf1, qf[1], a);
            s[rt] = a;
        }

        // ---- 2^s + cvt_pk pack into two MFMA32 B-frags ----
        short8 pf[2];
#pragma unroll
        for (int f = 0; f < 2; f++) {
            float e0 = fexp2(s[2 * f][0]),     e1 = fexp2(s[2 * f][1]);
            float e2 = fexp2(s[2 * f][2]),     e3 = fexp2(s[2 * f][3]);
            float e4 = fexp2(s[2 * f + 1][0]), e5 = fexp2(s[2 * f + 1][1]);
            float e6 = fexp2(s[2 * f + 1][2]), e7 = fexp2(s[2 * f + 1][3]);
            lsum += ((e0 + e1) + (e2 + e3)) + ((e4 + e5) + (e6 + e7));
            union { short8 s8; unsigned u[4]; } pk;
            pk.u[0] = pkbf(e0, e1);
            pk.u[1] = pkbf(e2, e3);
            pk.u[2] = pkbf(e4, e5);
            pk.u[3] = pkbf(e6, e7);
            pf[f] = pk.s8;
        }

        // ---- O^T += V^T @ P^T: 2 MFMA32 per dim-subtile ----
        __builtin_amdgcn_s_setprio(1);
#pragma unroll
        for (int dt = 0; dt < 4; dt++) {
            const int row = dt * 16 + lo16;
            const int rs = row & 7;
            short8 vf0 = *(const short8*)&sm[buf][8192 + row * 128 + ((quad ^ rs) * 16)];
            short8 vf1 = *(const short8*)&sm[buf][8192 + row * 128 + (((4 + quad) ^ rs) * 16)];
            f32x4 a = oacc[dt];
            a = MFMA32(vf0, pf[0], a);
            a = MFMA32(vf1, pf[1], a);
            oacc[dt] = a;
        }
        __builtin_amdgcn_s_setprio(0);
    }

    // deferred l reduction across quads (each quad covered disjoint keys)
    lsum += __shfl_xor(lsum, 16);
    lsum += __shfl_xor(lsum, 32);
    const float inv = 1.0f / lsum;

    // O^T[dim = dt*16 + quad*4 + r][query = lo16] -> ab bf16 [B,S,NX]
    unsigned short* dst = ab + (size_t)(b * SEQ + q0 + w * 16 + lo16) * NX + h * DHEAD;
#pragma unroll
    for (int dt = 0; dt < 4; dt++) {
        ushort4 pv;
        pv.x = f2bf(oacc[dt][0] * inv);
        pv.y = f2bf(oacc[dt][1] * inv);
        pv.z = f2bf(oacc[dt][2] * inv);
        pv.w = f2bf(oacc[dt][3] * inv);
        *(ushort4*)(dst + dt * 16 + quad * 4) = pv;
    }
}

// ---------------------------------------------------------------------------
extern "C" void kernel_launch(void* const* d_in, const int* in_sizes, int n_in,
                              void* d_out, int out_size, void* d_ws, size_t ws_size,
                              hipStream_t stream)
{
    const float* hs     = (const float*)d_in[0];
    const float* w_attn = (const float*)d_in[1];
    const float* b_attn = (const float*)d_in[2];
    const float* w_proj = (const float*)d_in[3];
    const float* b_proj = (const float*)d_in[4];
    float* out = (float*)d_out;

    unsigned short* wsu = (unsigned short*)d_ws;
    unsigned short* Abf  = wsu;                      // 4096*768
    unsigned short* WtA  = Abf  + 3145728;           // 2304*768
    unsigned short* WtP  = WtA  + 1769472;           // 768*768
    unsigned short* qbuf = WtP  + 589824;            // [B,H,S,D]
    unsigned short* kbuf = qbuf + 3145728;           // [B,H,S,D]
    unsigned short* vtbf = kbuf + 3145728;           // [B,H,D,S]
    unsigned short* abf  = vtbf + 3145728;           // [B,S,NX] bf16

    // merged converts (one dispatch)
    cvt_all<<<5376, 256, 0, stream>>>(hs, w_attn, w_proj, Abf, WtA, WtP);

    // QKV GEMM
    gemm_bf<0><<<dim3(18, 32), 256, 0, stream>>>(
        Abf, WtA, b_attn, nullptr, qbuf, kbuf, vtbf, MTOK, 3 * NX, NX);

    // attention
    attn_bf<<<768, 256, 0, stream>>>(qbuf, kbuf, vtbf, abf);

    // output projection
    gemm_bf<1><<<dim3(6, 32), 256, 0, stream>>>(
        abf, WtP, b_proj, out, nullptr, nullptr, nullptr, MTOK, NX, NX);
}